// Round 7
// baseline (323.255 us; speedup 1.0000x reference)
//
#include <hip/hip_runtime.h>
#include <cstdint>

typedef __bf16 bf16;
typedef __attribute__((ext_vector_type(8))) __bf16 bf16x8;
typedef __attribute__((ext_vector_type(4))) float f32x4;

#define MFMA16(a, b, c) __builtin_amdgcn_mfma_f32_16x16x32_bf16(a, b, c, 0, 0, 0)

// async global->LDS, 16B per lane; LDS dest = wave-uniform base + lane*16.
__device__ __forceinline__ void async16(const bf16* g, bf16* l) {
  __builtin_amdgcn_global_load_lds(
      (const __attribute__((address_space(1))) void*)g,
      (__attribute__((address_space(3))) void*)l, 16, 0, 0);
}

__device__ __forceinline__ bf16x8 load8cvt(const float* p) {
  f32x4 a = *(const f32x4*)p;
  f32x4 b = *(const f32x4*)(p + 4);
  bf16x8 r;
  r[0] = (bf16)a[0]; r[1] = (bf16)a[1]; r[2] = (bf16)a[2]; r[3] = (bf16)a[3];
  r[4] = (bf16)b[0]; r[5] = (bf16)b[1]; r[6] = (bf16)b[2]; r[7] = (bf16)b[3];
  return r;
}

// ---------------------------------------------------------------------------
// fp32 -> bf16 elementwise convert (8 elems/thread).
// ---------------------------------------------------------------------------
__global__ __launch_bounds__(256) void cvt_f32_bf16(const float* __restrict__ src,
                                                    bf16* __restrict__ dst, int n) {
  int i = (blockIdx.x * 256 + threadIdx.x) * 8;
  if (i >= n) return;
  *(bf16x8*)(dst + i) = load8cvt(src + i);
}

// 6 converts in one launch (blockIdx.y selects segment; spare blocks exit).
__global__ __launch_bounds__(256) void cvt6(
    const float* __restrict__ s0, bf16* __restrict__ d0, int n0,
    const float* __restrict__ s1, bf16* __restrict__ d1, int n1,
    const float* __restrict__ s2, bf16* __restrict__ d2, int n2,
    const float* __restrict__ s3, bf16* __restrict__ d3, int n3,
    const float* __restrict__ s4, bf16* __restrict__ d4, int n4,
    const float* __restrict__ s5, bf16* __restrict__ d5, int n5) {
  const float* s; bf16* d; int n;
  switch (blockIdx.y) {
    case 0: s = s0; d = d0; n = n0; break;
    case 1: s = s1; d = d1; n = n1; break;
    case 2: s = s2; d = d2; n = n2; break;
    case 3: s = s3; d = d3; n = n3; break;
    case 4: s = s4; d = d4; n = n4; break;
    default: s = s5; d = d5; n = n5; break;
  }
  int i = (blockIdx.x * 256 + threadIdx.x) * 8;
  if (i >= n) return;
  *(bf16x8*)(d + i) = load8cvt(s + i);
}

// ---------------------------------------------------------------------------
// C = A @ B^T + bias. Both operands bf16, staged via global_load_lds x16.
// 128x64 tile, BK=32, 4 waves of 64x32. RING-4 double... quad-buffer:
// prologue stages tiles 0..2 (9 loads/wave in flight); steady state issues
// tile s+3 then waits vmcnt(9) (= tile s's 3 loads done, 9 stay in flight
// across the barrier). Staging is issued ~3 phases ahead -> L3/HBM latency
// covered (round-6 counters: 13% MfmaUtil = latency exposed at depth-1).
// Buffer reuse safety: tile s+3 -> buf (s+3)&3 = (s-1)&3, whose reads were
// fenced by iter s-1's lgkmcnt(0)+barrier (precedes this issue). K mult of 32.
// bias(n) = n < nsplit ? bias0[n] : bias1[n - nsplit]  (GEMM fusion support).
// MODE 0: bf16 out. MODE 1: fp32 out (stride ldo). MODE 2: bf16 + fp32 n<nsplit.
// ---------------------------------------------------------------------------
template <int MODE>
__global__ __launch_bounds__(256) void gemm_bb(
    const bf16* __restrict__ A, int lda,
    const bf16* __restrict__ Bm, int ldb,
    const float* __restrict__ bias0, const float* __restrict__ bias1, int nsplit,
    bf16* __restrict__ outb, float* __restrict__ outf, int ldo,
    int M, int N, int K) {
  __shared__ __align__(16) bf16 As[4][128 * 32];
  __shared__ __align__(16) bf16 Bs[4][64 * 32];
  const int t = threadIdx.x;
  const int lane = t & 63, w = t >> 6;
  const int quad = lane >> 4, l15 = lane & 15;

  // XCD-aware chunked swizzle (all call-site grids have nwg % 8 == 0).
  const int nwg = gridDim.x * gridDim.y;
  const int id = blockIdx.y * gridDim.x + blockIdx.x;
  const int sw = (id & 7) * (nwg >> 3) + (id >> 3);
  const int bm = (sw / gridDim.x) * 128, bn = (sw % gridDim.x) * 64;

  const int wm = (w >> 1) * 64, wn = (w & 1) * 32;

  f32x4 acc[4][2] = {};

  // staging map: thread t covers row t/4, cols (t%4)*8..+7
  const int srow = t >> 2;
  const int scol = (t & 3) * 8;
  const bf16* Ap = A + (int64_t)(bm + srow) * lda + scol;
  const bf16* Bp = Bm + (int64_t)(bn + srow) * ldb + scol;

  auto STAGE = [&](int buf, int k0) {
    async16(Ap + k0, &As[buf][w * 512]);                             // A rows 0..63
    async16(Ap + (int64_t)64 * lda + k0, &As[buf][2048 + w * 512]);  // A rows 64..127
    async16(Bp + k0, &Bs[buf][w * 512]);                             // B rows 0..63
  };
  auto COMPUTE = [&](int buf) {
    bf16x8 a[4], bq[2];
#pragma unroll
    for (int mt = 0; mt < 4; ++mt)
      a[mt] = *(const bf16x8*)(&As[buf][(wm + mt * 16 + l15) * 32 + quad * 8]);
#pragma unroll
    for (int nt = 0; nt < 2; ++nt)
      bq[nt] = *(const bf16x8*)(&Bs[buf][(wn + nt * 16 + l15) * 32 + quad * 8]);
#pragma unroll
    for (int mt = 0; mt < 4; ++mt)
#pragma unroll
      for (int nt = 0; nt < 2; ++nt)
        acc[mt][nt] = MFMA16(a[mt], bq[nt], acc[mt][nt]);
  };

  const int K32 = K >> 5;
  STAGE(0, 0);
  STAGE(1, 32);
  STAGE(2, 64);   // 9 loads/wave in flight
  for (int s = 0; s < K32; ++s) {
    if (s + 3 < K32) {
      STAGE((s + 3) & 3, (s + 3) << 5);   // 12 in flight
      // tile s's 3 oldest done; 9 (tiles s+1..s+3) stay in flight across barrier
      asm volatile("s_waitcnt vmcnt(9)\n\ts_barrier" ::: "memory");
    } else {
      const int rem = K32 - 1 - s;        // tiles in flight beyond current
      if (rem >= 2)      asm volatile("s_waitcnt vmcnt(6)\n\ts_barrier" ::: "memory");
      else if (rem == 1) asm volatile("s_waitcnt vmcnt(3)\n\ts_barrier" ::: "memory");
      else               asm volatile("s_waitcnt vmcnt(0)\n\ts_barrier" ::: "memory");
    }
    COMPUTE(s & 3);
    // all LDS reads of this buffer retired before its next overwrite
    asm volatile("s_waitcnt lgkmcnt(0)\n\ts_barrier" ::: "memory");
  }

  float bv[2];
#pragma unroll
  for (int nt = 0; nt < 2; ++nt) {
    int n = bn + wn + nt * 16 + l15;
    bv[nt] = (n < nsplit) ? bias0[n] : bias1[n - nsplit];
  }
#pragma unroll
  for (int mt = 0; mt < 4; ++mt)
#pragma unroll
    for (int nt = 0; nt < 2; ++nt)
#pragma unroll
      for (int r = 0; r < 4; ++r) {
        // C/D layout (m89/m91 verified): row = quad*4+r, col = lane&15
        int64_t m = bm + wm + mt * 16 + quad * 4 + r;
        int n = bn + wn + nt * 16 + l15;
        float v = acc[mt][nt][r] + bv[nt];
        if (MODE != 1) outb[m * ldo + n] = (bf16)v;
        if (MODE == 1) outf[m * (int64_t)ldo + n] = v;
        if (MODE == 2 && n < nsplit) outf[m * nsplit + n] = v;
      }
}

// ---------------------------------------------------------------------------
// k_r = rope(k @ W_KR^T + b_KR), fp32 out. K lives in fused KV buffer:
// element (token, h, d) = kmat[token*4096 + h*128 + d].
// ---------------------------------------------------------------------------
__global__ __launch_bounds__(256) void kr_rope(const bf16* __restrict__ kmat,
                                               const float* __restrict__ Wkr,
                                               const float* __restrict__ bkr,
                                               float* __restrict__ krout) {
  const int t = threadIdx.x;
  const int lane = t & 63, w = t >> 6;
  const int quad = lane >> 4, l15 = lane & 15;
  const int row0 = blockIdx.x * 64 + w * 16;

  const int rr = row0 + l15;  // flattened row = token*16 + h
  const bf16* krow = kmat + (int64_t)(rr >> 4) * 4096 + (rr & 15) * 128;
  bf16x8 af[4];
#pragma unroll
  for (int ks = 0; ks < 4; ++ks)
    af[ks] = *(const bf16x8*)(krow + ks * 32 + quad * 8);

  f32x4 acc[4] = {};
#pragma unroll
  for (int nt = 0; nt < 4; ++nt)
#pragma unroll
    for (int ks = 0; ks < 4; ++ks) {
      bf16x8 bf_ = load8cvt(Wkr + (nt * 16 + l15) * 128 + ks * 32 + quad * 8);
      acc[nt] = MFMA16(af[ks], bf_, acc[nt]);
    }

  float bv[4], fr[4];
#pragma unroll
  for (int nt = 0; nt < 4; ++nt) {
    bv[nt] = bkr[nt * 16 + l15];
    int j = ((nt & 1) * 16 + l15);  // n mod 32
    fr[nt] = exp2f(-(float)j * 0.41524101186092034f);  // 10000^(-j/32)
  }

#pragma unroll
  for (int r = 0; r < 4; ++r) {
    int row = row0 + quad * 4 + r;   // row = token*16 + h
    int pos = (row >> 4) & 1023;     // s = token mod 1024
    float val[4];
#pragma unroll
    for (int nt = 0; nt < 4; ++nt) val[nt] = acc[nt][r] + bv[nt];
#pragma unroll
    for (int nt = 0; nt < 4; ++nt) {
      int n = nt * 16 + l15;
      float ang = (float)pos * fr[nt];
      float c = cosf(ang), s = sinf(ang);
      float partner = val[nt ^ 2];  // col (n+32)%64 lives in fragment nt^2
      float o = val[nt] * c + ((nt < 2) ? -partner : partner) * s;
      krout[(int64_t)row * 64 + n] = o;
    }
  }
}

// ---------------------------------------------------------------------------
// Attention. Grid (8 xcd-slots, 64), 4 waves/block, 64 q-rows/block.
// Round-6 structure kept (K via global_load_lds + pre-swizzled source, linear
// LDS; V reg-scatter into XOR-swizzled Vt; Pl block-swizzled; counted-wait end
// barrier). Change: 512 blocks -> 2 blocks/CU (LDS 60KB). Same 8 waves/CU as
// round 6 but DECOUPLED barrier domains: one block computes while the other
// waits (round-6 counters: all pipes <20% at 1 block/CU = lockstep stall).
// XCD pinning: 4 bh x 16 qt per XCD -> K/V ~2MB L2-resident per XCD.
// ---------------------------------------------------------------------------
__global__ __launch_bounds__(256, 2) void attn_fwd(const bf16* __restrict__ q,
                                                   const bf16* __restrict__ k,
                                                   const bf16* __restrict__ v,
                                                   bf16* __restrict__ attn) {
  const int bh = blockIdx.x * 4 + (blockIdx.y >> 4);  // 4 bh per XCD slot
  const int qt = blockIdx.y & 15;                     // 16 q-tiles of 64 rows
  const int b = bh >> 4, h = bh & 15;
  __shared__ __align__(16) bf16 Kb[2][64 * 128];  // linear, src-swizzled (32KB)
  __shared__ __align__(16) bf16 Vt[128 * 72];     // [d][key-swizzled]
  __shared__ __align__(16) bf16 Pl[4][16 * 72];   // per-wave P, block-swizzled

  const int t = threadIdx.x;
  const int lane = t & 63, w = t >> 6;          // w in 0..3
  const int quad = lane >> 4, l15 = lane & 15;
  const int trow = b * 1024 + qt * 64 + w * 16;
  const float scale = 0.08838834764831845f;      // 1/sqrt(128)

  bf16x8 qf[4];
#pragma unroll
  for (int ks = 0; ks < 4; ++ks)
    qf[ks] = *(const bf16x8*)(q + (int64_t)(trow + l15) * 2048 + h * 128 +
                              ks * 32 + quad * 8);

  const bf16* kbase = k + (int64_t)b * 1024 * 4096 + h * 128;
  // K-DMA: wave w covers rows w*16 + c*4 + (lane>>4), c = 0..3 (4 rows/call).
  // Source pre-swizzle: slot l&15 holds logical chunk (l&15)^(row&7).
  const int lrow = lane >> 4;
  int64_t koff[4];
#pragma unroll
  for (int c = 0; c < 4; ++c) {
    int row = w * 16 + c * 4 + lrow;
    koff[c] = (int64_t)row * 4096 + (((lane & 15) ^ (row & 7)) << 3);
  }

  // V staging: thread covers keys r*16 + (t>>4), cols (t&15)*8..+7, r=0..3
  const int skey = t >> 4;        // 0..15
  const int sd0 = (t & 15) * 8;
  const bf16* vp = v + (int64_t)b * 1024 * 4096 + h * 128 + sd0;

  // prologue: tile 0 staging in flight
#pragma unroll
  for (int c = 0; c < 4; ++c)
    async16(kbase + koff[c], &Kb[0][w * 2048 + c * 512]);
  bf16x8 vreg[4];
#pragma unroll
  for (int r = 0; r < 4; ++r)
    vreg[r] = *(const bf16x8*)(vp + (int64_t)(r * 16 + skey) * 4096);

  f32x4 o[8] = {};
  float lrw[4] = {0.f, 0.f, 0.f, 0.f};

  for (int kt = 0; kt < 16; ++kt) {
    const int cur = kt & 1;
    // V scatter (vreg use + __syncthreads drains vmcnt incl. this tile's K-DMA)
#pragma unroll
    for (int r = 0; r < 4; ++r) {
      int key = r * 16 + skey;
      int col = (((key >> 3) ^ ((sd0 >> 3) & 7)) << 3) + (key & 7);
#pragma unroll
      for (int j = 0; j < 8; ++j) Vt[(sd0 + j) * 72 + col] = vreg[r][j];
    }
    __syncthreads();  // vmcnt(0)+lgkmcnt(0)+barrier: K tile + V tile visible

    // issue next tile's staging; latency hides under QK + softmax + PV
    if (kt + 1 < 16) {
      const bf16* kn = kbase + (int64_t)(kt + 1) * 64 * 4096;
#pragma unroll
      for (int c = 0; c < 4; ++c)
        async16(kn + koff[c], &Kb[cur ^ 1][w * 2048 + c * 512]);
#pragma unroll
      for (int r = 0; r < 4; ++r)
        vreg[r] = *(const bf16x8*)(vp + (int64_t)((kt + 1) * 64 + r * 16 + skey) * 4096);
    }

    // S = Q @ K^T  (16 x 64 per wave); K from swizzled LDS
    f32x4 s[4] = {};
    __builtin_amdgcn_s_setprio(1);
#pragma unroll
    for (int nt = 0; nt < 4; ++nt)
#pragma unroll
      for (int ks = 0; ks < 4; ++ks) {
        int key = nt * 16 + l15;
        bf16x8 bfrg = *(const bf16x8*)(
            &Kb[cur][key * 128 + (((ks * 4 + quad) ^ (l15 & 7)) << 3)]);
        s[nt] = MFMA16(qf[ks], bfrg, s[nt]);
      }
    __builtin_amdgcn_s_setprio(0);

    // p = exp(s*scale); lane-local row partials; stash P (block-swizzled)
    float rsum[4] = {0.f, 0.f, 0.f, 0.f};
#pragma unroll
    for (int nt = 0; nt < 4; ++nt)
#pragma unroll
      for (int r = 0; r < 4; ++r) {
        float p = __expf(s[nt][r] * scale);
        rsum[r] += p;
        int row = quad * 4 + r;
        int blk = (nt * 2 + (l15 >> 3)) ^ (quad * 2 + (r >> 1));
        Pl[w][row * 72 + (blk << 3) + (l15 & 7)] = (bf16)p;
      }
#pragma unroll
    for (int r = 0; r < 4; ++r) lrw[r] += rsum[r];

    // O += P @ V   (Pl is wave-private: in-wave lgkm ordering suffices)
    __builtin_amdgcn_s_setprio(1);
#pragma unroll
    for (int ks = 0; ks < 2; ++ks) {
      int ablk = (ks * 4 + quad) ^ (l15 >> 1);
      bf16x8 afrg = *(const bf16x8*)(&Pl[w][l15 * 72 + (ablk << 3)]);
#pragma unroll
      for (int dt = 0; dt < 8; ++dt) {
        int d = dt * 16 + l15;
        int kb = ((ks * 4 + quad) ^ ((d >> 3) & 7)) << 3;
        bf16x8 bfrg = *(const bf16x8*)(Vt + d * 72 + kb);
        o[dt] = MFMA16(afrg, bfrg, o[dt]);
      }
    }
    __builtin_amdgcn_s_setprio(0);
    // raw barrier WITHOUT vmcnt drain: next-tile K-DMA + V loads stay in
    // flight. lgkmcnt(0) = this wave's LDS reads retired; barrier = all waves.
    asm volatile("s_waitcnt lgkmcnt(0)\n\ts_barrier" ::: "memory");
  }

  float inv[4];
#pragma unroll
  for (int r = 0; r < 4; ++r) {
    float ssum = lrw[r];
#pragma unroll
    for (int off = 8; off >= 1; off >>= 1) ssum += __shfl_xor(ssum, off, 64);
    inv[r] = 1.0f / ssum;
  }
#pragma unroll
  for (int dt = 0; dt < 8; ++dt)
#pragma unroll
    for (int r = 0; r < 4; ++r) {
      int64_t row = trow + quad * 4 + r;
      int col = h * 128 + dt * 16 + l15;
      attn[row * 2048 + col] = (bf16)(o[dt][r] * inv[r]);
    }
}

// ---------------------------------------------------------------------------
extern "C" void kernel_launch(void* const* d_in, const int* in_sizes, int n_in,
                              void* d_out, int out_size, void* d_ws, size_t ws_size,
                              hipStream_t stream) {
  const float* hidden = (const float*)d_in[0];
  const float* Wdkv = (const float*)d_in[1];
  const float* bdkv = (const float*)d_in[2];
  const float* Wuk  = (const float*)d_in[3];
  const float* buk  = (const float*)d_in[4];
  const float* Wuv  = (const float*)d_in[5];
  const float* buv  = (const float*)d_in[6];
  const float* Wkr  = (const float*)d_in[7];
  const float* bkr  = (const float*)d_in[8];
  const float* Wdq  = (const float*)d_in[9];
  const float* bdq  = (const float*)d_in[10];
  const float* Wuq  = (const float*)d_in[11];
  const float* buq  = (const float*)d_in[12];
  // d_in[13], d_in[14] (W_QR_w/b): dead code in the reference.
  const float* Wo   = (const float*)d_in[15];
  const float* bo   = (const float*)d_in[16];

  // Outputs fp32.
  float* out0 = (float*)d_out;          // [2048][2048]
  float* c_kv = out0 + 4194304;         // [2048][512]
  float* k_r  = out0 + 5242880;         // [32768][64]

  // ---- workspace (25.2 MB) ----
  bf16* DKVQ = (bf16*)d_ws;             // [2048][2048]: cols 0-511 = c_kv bf16,
                                        // cols 512+ = c_q. Later reused for attn out.
  bf16* KV   = DKVQ + 4194304;          // [2048][4096]: cols 0-2047 K, 2048+ V

  // ---- transient aliases (lifetimes verified non-overlapping) ----
  bf16* WT   = KV;                      // Wdkv+Wdq bf16 [2048][2048]; dead before KV gemm writes
  bf16* qx   = (bf16*)out0;             // [2048][2048] q (written by UQ gemm)
  bf16* hb   = qx + 4194304;            // hidden bf16; after DKVQ gemm reused for Wuq bf16
  bf16* WUKV = qx;                      // Wuk+Wuv bf16 [4096][512]; dead before UQ gemm writes qx
  bf16* Wuqb = hb;                      // Wuq bf16 [2048][1536]
  bf16* Wob  = (bf16*)k_r;              // Wo bf16 [2048][2048]; k_r written after final gemm

  // 1. all leading converts in one launch: hidden, Wdkv, Wdq, Wuk, Wuv, Wo
  cvt6<<<dim3(2048, 6), 256, 0, stream>>>(
      hidden, hb, 4194304,
      Wdkv, WT, 1048576,
      Wdq, WT + 1048576, 3145728,
      Wuk, WUKV, 1048576,
      Wuv, WUKV + 1048576, 1048576,
      Wo, Wob, 4194304);
  // 2. fused c_kv|c_q gemm: [2048][2048] = hb @ WT^T. fp32 c_kv for n<512.
  gemm_bb<2><<<dim3(32, 16), 256, 0, stream>>>(hb, 2048, WT, 2048, bdkv, bdq, 512,
                                               DKVQ, c_kv, 2048, 2048, 2048, 2048);
  // 3. W_UQ -> bf16 (hb region; hidden bf16 consumed by step 2)
  cvt_f32_bf16<<<1536, 256, 0, stream>>>(Wuq, Wuqb, 3145728);
  // 4. fused K|V gemm: [2048][4096] = ckv_bf @ WUKV^T (1024 blocks)
  gemm_bb<0><<<dim3(64, 16), 256, 0, stream>>>(DKVQ, 2048, WUKV, 512, buk, buv, 2048,
                                               KV, nullptr, 4096, 2048, 4096, 512);
  // 5. q gemm: qx = cq @ Wuq^T (A = DKVQ cols 512+, lda 2048)
  gemm_bb<0><<<dim3(32, 16), 256, 0, stream>>>(DKVQ + 512, 2048, Wuqb, 1536, buq, buq,
                                               2048, qx, nullptr, 2048, 2048, 2048, 1536);
  // 6. attention -> DKVQ region (c_kv/c_q bf16 now dead)
  attn_fwd<<<dim3(8, 64), 256, 0, stream>>>(qx, KV, KV + 2048, DKVQ);
  // 7. output gemm: out0 = attn @ Wo^T (overwrites qx/hb regions, both dead)
  gemm_bb<1><<<dim3(32, 16), 256, 0, stream>>>(DKVQ, 2048, Wob, 2048, bo, bo, 2048,
                                               nullptr, out0, 2048, 2048, 2048, 2048);
  // 8. k_r rope (reads KV; overwrites Wob which is now dead)
  kr_rope<<<512, 256, 0, stream>>>(KV, Wkr, bkr, k_r);
}

// Round 8
// 284.702 us; speedup vs baseline: 1.1354x; 1.1354x over previous
//
#include <hip/hip_runtime.h>
#include <cstdint>

typedef __bf16 bf16;
typedef __attribute__((ext_vector_type(8))) __bf16 bf16x8;
typedef __attribute__((ext_vector_type(4))) float f32x4;

#define MFMA16(a, b, c) __builtin_amdgcn_mfma_f32_16x16x32_bf16(a, b, c, 0, 0, 0)

// async global->LDS, 16B per lane; LDS dest = wave-uniform base + lane*16.
__device__ __forceinline__ void async16(const bf16* g, bf16* l) {
  __builtin_amdgcn_global_load_lds(
      (const __attribute__((address_space(1))) void*)g,
      (__attribute__((address_space(3))) void*)l, 16, 0, 0);
}

__device__ __forceinline__ bf16x8 load8cvt(const float* p) {
  f32x4 a = *(const f32x4*)p;
  f32x4 b = *(const f32x4*)(p + 4);
  bf16x8 r;
  r[0] = (bf16)a[0]; r[1] = (bf16)a[1]; r[2] = (bf16)a[2]; r[3] = (bf16)a[3];
  r[4] = (bf16)b[0]; r[5] = (bf16)b[1]; r[6] = (bf16)b[2]; r[7] = (bf16)b[3];
  return r;
}

// ---------------------------------------------------------------------------
// fp32 -> bf16 elementwise convert (8 elems/thread).
// ---------------------------------------------------------------------------
__global__ __launch_bounds__(256) void cvt_f32_bf16(const float* __restrict__ src,
                                                    bf16* __restrict__ dst, int n) {
  int i = (blockIdx.x * 256 + threadIdx.x) * 8;
  if (i >= n) return;
  *(bf16x8*)(dst + i) = load8cvt(src + i);
}

// 6 converts in one launch (blockIdx.y selects segment; spare blocks exit).
__global__ __launch_bounds__(256) void cvt6(
    const float* __restrict__ s0, bf16* __restrict__ d0, int n0,
    const float* __restrict__ s1, bf16* __restrict__ d1, int n1,
    const float* __restrict__ s2, bf16* __restrict__ d2, int n2,
    const float* __restrict__ s3, bf16* __restrict__ d3, int n3,
    const float* __restrict__ s4, bf16* __restrict__ d4, int n4,
    const float* __restrict__ s5, bf16* __restrict__ d5, int n5) {
  const float* s; bf16* d; int n;
  switch (blockIdx.y) {
    case 0: s = s0; d = d0; n = n0; break;
    case 1: s = s1; d = d1; n = n1; break;
    case 2: s = s2; d = d2; n = n2; break;
    case 3: s = s3; d = d3; n = n3; break;
    case 4: s = s4; d = d4; n = n4; break;
    default: s = s5; d = d5; n = n5; break;
  }
  int i = (blockIdx.x * 256 + threadIdx.x) * 8;
  if (i >= n) return;
  *(bf16x8*)(d + i) = load8cvt(s + i);
}

// ---------------------------------------------------------------------------
// C = A @ B^T + bias. Both bf16, staged via global_load_lds x16.
// 128x64 tile, BK=64 (128B LDS rows!), 4 waves of 64x32.
// Round-7 diagnosis: at BK=32 (64B rows) the b128 reads were ~8-way bank
// conflicted (row*16+quad*4 mod 32 -> 2 banks per phase; 3.1M conflict cy).
// BK=64 gives 8 chunks/row -> chunk^(row&7) source-pre-swizzle -> 2-way (free).
// Double-buffered, counted vmcnt(6): next tile's 6 loads stay in flight.
// K mult of 64 (call sites 2048/1536/512).
// bias(n) = n < nsplit ? bias0[n] : bias1[n-nsplit].
// MODE 0: bf16 out. MODE 1: fp32 out (stride ldo). MODE 2: bf16 + fp32 n<nsplit.
// TRANSV: blocks with bn >= nsplit store the tile TRANSPOSED to
// outb[(n-nsplit)*ldo + nsplit + m] via an LDS bounce (produces V^T for attn).
// ---------------------------------------------------------------------------
template <int MODE, bool TRANSV>
__global__ __launch_bounds__(256) void gemm_bb(
    const bf16* __restrict__ A, int lda,
    const bf16* __restrict__ Bm, int ldb,
    const float* __restrict__ bias0, const float* __restrict__ bias1, int nsplit,
    bf16* __restrict__ outb, float* __restrict__ outf, int ldo,
    int M, int N, int K) {
  __shared__ __align__(16) bf16 As[2][128 * 64];   // 32 KB
  __shared__ __align__(16) bf16 Bs[2][64 * 64];    // 16 KB
  const int t = threadIdx.x;
  const int lane = t & 63, w = t >> 6;
  const int quad = lane >> 4, l15 = lane & 15;

  // XCD-aware chunked swizzle (all call-site grids have nwg % 8 == 0).
  const int nwg = gridDim.x * gridDim.y;
  const int id = blockIdx.y * gridDim.x + blockIdx.x;
  const int sw = (id & 7) * (nwg >> 3) + (id >> 3);
  const int bm = (sw / gridDim.x) * 128, bn = (sw % gridDim.x) * 64;

  const int wm = (w >> 1) * 64, wn = (w & 1) * 32;

  f32x4 acc[4][2] = {};

  // staging: each call covers 8 rows x 128B. lane: row8 = lane>>3, slot lane&7;
  // slot holds logical chunk slot^(row&7); row&7 == (lane>>3)&7 for all calls.
  const int r8 = lane >> 3;
  const int sc = ((lane & 7) ^ (r8 & 7)) * 8;
  const bf16* Ap = A + (int64_t)(bm + w * 32 + r8) * lda + sc;
  const bf16* Bp = Bm + (int64_t)(bn + w * 16 + r8) * ldb + sc;

  auto STAGE = [&](int buf, int k0) {
#pragma unroll
    for (int a = 0; a < 4; ++a)   // A rows w*32 .. w*32+31
      async16(Ap + (int64_t)(a * 8) * lda + k0, &As[buf][(w * 32 + a * 8) * 64]);
#pragma unroll
    for (int bq = 0; bq < 2; ++bq)  // B rows w*16 .. w*16+15
      async16(Bp + (int64_t)(bq * 8) * ldb + k0, &Bs[buf][(w * 16 + bq * 8) * 64]);
  };
  auto COMPUTE = [&](int buf) {
    bf16x8 a[4][2], bb[2][2];
#pragma unroll
    for (int mt = 0; mt < 4; ++mt)
#pragma unroll
      for (int ks = 0; ks < 2; ++ks) {
        int row = wm + mt * 16 + l15;
        a[mt][ks] = *(const bf16x8*)(
            &As[buf][row * 64 + (((ks * 4 + quad) ^ (l15 & 7)) << 3)]);
      }
#pragma unroll
    for (int nt = 0; nt < 2; ++nt)
#pragma unroll
      for (int ks = 0; ks < 2; ++ks) {
        int row = wn + nt * 16 + l15;
        bb[nt][ks] = *(const bf16x8*)(
            &Bs[buf][row * 64 + (((ks * 4 + quad) ^ (l15 & 7)) << 3)]);
      }
#pragma unroll
    for (int ks = 0; ks < 2; ++ks)
#pragma unroll
      for (int mt = 0; mt < 4; ++mt)
#pragma unroll
        for (int nt = 0; nt < 2; ++nt)
          acc[mt][nt] = MFMA16(a[mt][ks], bb[nt][ks], acc[mt][nt]);
  };

  const int KS = K >> 6;
  STAGE(0, 0);  // 6 loads in flight
  for (int s = 0; s < KS; ++s) {
    if (s + 1 < KS) {
      STAGE((s + 1) & 1, (s + 1) << 6);  // 12 in flight
      // current tile's 6 oldest done; next's 6 stay in flight across barrier
      asm volatile("s_waitcnt vmcnt(6)\n\ts_barrier" ::: "memory");
    } else {
      asm volatile("s_waitcnt vmcnt(0)\n\ts_barrier" ::: "memory");
    }
    COMPUTE(s & 1);
    asm volatile("s_waitcnt lgkmcnt(0)\n\ts_barrier" ::: "memory");
  }

  float bv[2];
#pragma unroll
  for (int nt = 0; nt < 2; ++nt) {
    int n = bn + wn + nt * 16 + l15;
    bv[nt] = (n < nsplit) ? bias0[n] : bias1[n - nsplit];
  }

  if (TRANSV && bn >= nsplit) {
    // transposed store via LDS bounce (one-time; Ls reuses As, padded rows).
    bf16* Ls = (bf16*)As;  // [64 n][136 m] bf16 = 17.4 KB
#pragma unroll
    for (int mt = 0; mt < 4; ++mt)
#pragma unroll
      for (int nt = 0; nt < 2; ++nt)
#pragma unroll
        for (int r = 0; r < 4; ++r)
          Ls[(wn + nt * 16 + l15) * 136 + wm + mt * 16 + quad * 4 + r] =
              (bf16)(acc[mt][nt][r] + bv[nt]);
    __syncthreads();
    const int rloc = t >> 2;            // local n (0..63)
    const int cb = (t & 3) * 32;        // local m chunk
#pragma unroll
    for (int c = 0; c < 4; ++c) {
      bf16x8 val = *(const bf16x8*)(Ls + rloc * 136 + cb + c * 8);
      *(bf16x8*)(outb + (int64_t)(bn - nsplit + rloc) * ldo + nsplit + bm + cb + c * 8) = val;
    }
    return;
  }

#pragma unroll
  for (int mt = 0; mt < 4; ++mt)
#pragma unroll
    for (int nt = 0; nt < 2; ++nt)
#pragma unroll
      for (int r = 0; r < 4; ++r) {
        // C/D layout (m89/m91 verified): row = quad*4+r, col = lane&15
        int64_t m = bm + wm + mt * 16 + quad * 4 + r;
        int n = bn + wn + nt * 16 + l15;
        float v = acc[mt][nt][r] + bv[nt];
        if (MODE != 1) outb[m * ldo + n] = (bf16)v;
        if (MODE == 1) outf[m * (int64_t)ldo + n] = v;
        if (MODE == 2 && n < nsplit) outf[m * nsplit + n] = v;
      }
}

// ---------------------------------------------------------------------------
// k_r = rope(k @ W_KR^T + b_KR), fp32 out. K lives in fused KV buffer:
// element (token, h, d) = kmat[token*4096 + h*128 + d].
// ---------------------------------------------------------------------------
__global__ __launch_bounds__(256) void kr_rope(const bf16* __restrict__ kmat,
                                               const float* __restrict__ Wkr,
                                               const float* __restrict__ bkr,
                                               float* __restrict__ krout) {
  const int t = threadIdx.x;
  const int lane = t & 63, w = t >> 6;
  const int quad = lane >> 4, l15 = lane & 15;
  const int row0 = blockIdx.x * 64 + w * 16;

  const int rr = row0 + l15;  // flattened row = token*16 + h
  const bf16* krow = kmat + (int64_t)(rr >> 4) * 4096 + (rr & 15) * 128;
  bf16x8 af[4];
#pragma unroll
  for (int ks = 0; ks < 4; ++ks)
    af[ks] = *(const bf16x8*)(krow + ks * 32 + quad * 8);

  f32x4 acc[4] = {};
#pragma unroll
  for (int nt = 0; nt < 4; ++nt)
#pragma unroll
    for (int ks = 0; ks < 4; ++ks) {
      bf16x8 bf_ = load8cvt(Wkr + (nt * 16 + l15) * 128 + ks * 32 + quad * 8);
      acc[nt] = MFMA16(af[ks], bf_, acc[nt]);
    }

  float bv[4], fr[4];
#pragma unroll
  for (int nt = 0; nt < 4; ++nt) {
    bv[nt] = bkr[nt * 16 + l15];
    int j = ((nt & 1) * 16 + l15);  // n mod 32
    fr[nt] = exp2f(-(float)j * 0.41524101186092034f);  // 10000^(-j/32)
  }

#pragma unroll
  for (int r = 0; r < 4; ++r) {
    int row = row0 + quad * 4 + r;   // row = token*16 + h
    int pos = (row >> 4) & 1023;     // s = token mod 1024
    float val[4];
#pragma unroll
    for (int nt = 0; nt < 4; ++nt) val[nt] = acc[nt][r] + bv[nt];
#pragma unroll
    for (int nt = 0; nt < 4; ++nt) {
      int n = nt * 16 + l15;
      float ang = (float)pos * fr[nt];
      float c = cosf(ang), s = sinf(ang);
      float partner = val[nt ^ 2];  // col (n+32)%64 lives in fragment nt^2
      float o = val[nt] * c + ((nt < 2) ? -partner : partner) * s;
      krout[(int64_t)row * 64 + n] = o;
    }
  }
}

// ---------------------------------------------------------------------------
// Attention. Grid (8 xcd-slots, 64), 4 waves/block, 64 q-rows/block.
// V is consumed from the V^T buffer the KV GEMM produced (TRANSV epilogue):
// vt[d_global*4096 + token]. Both K and V^T staged via global_load_lds with
// chunk^(row&7) source pre-swizzle into linear LDS -> QK and PV are both
// conflict-free ds_read_b128. No scatter, no reg-staging of V (rounds 3-7:
// the 32x ds_write_b16 V-transpose scatter dominated the LDS pipe).
// Counted vmcnt(8): next tile's 8 DMA calls stay in flight across barriers.
// XCD pinning: 4 bh per XCD slot -> K/V ~2MB L2-resident.
// ---------------------------------------------------------------------------
__global__ __launch_bounds__(256, 2) void attn_fwd(const bf16* __restrict__ q,
                                                   const bf16* __restrict__ k,
                                                   const bf16* __restrict__ vt,
                                                   bf16* __restrict__ attn) {
  const int bh = blockIdx.x * 4 + (blockIdx.y >> 4);  // 4 bh per XCD slot
  const int qt = blockIdx.y & 15;                     // 16 q-tiles of 64 rows
  const int b = bh >> 4, h = bh & 15;
  __shared__ __align__(16) bf16 Kb[2][64 * 128];  // [key][d], src-swizzled, 32KB
  __shared__ __align__(16) bf16 Vb[2][128 * 64];  // [d][key], src-swizzled, 32KB
  __shared__ __align__(16) bf16 Pl[4][16 * 72];   // per-wave P, block-swizzled

  const int t = threadIdx.x;
  const int lane = t & 63, w = t >> 6;          // w in 0..3
  const int quad = lane >> 4, l15 = lane & 15;
  const int trow = b * 1024 + qt * 64 + w * 16;
  const float scale = 0.08838834764831845f;      // 1/sqrt(128)

  bf16x8 qf[4];
#pragma unroll
  for (int ks = 0; ks < 4; ++ks)
    qf[ks] = *(const bf16x8*)(q + (int64_t)(trow + l15) * 2048 + h * 128 +
                              ks * 32 + quad * 8);

  // K DMA: wave w covers rows w*16+c*4+(lane>>4), 16 chunks of 8 per 256B row;
  // slot lane&15 holds logical chunk (lane&15)^(row&7).
  const bf16* kbase = k + (int64_t)b * 1024 * 4096 + h * 128;
  const int lr4 = lane >> 4;
  int64_t koff[4];
#pragma unroll
  for (int c = 0; c < 4; ++c) {
    int row = w * 16 + c * 4 + lr4;
    koff[c] = (int64_t)row * 4096 + (((lane & 15) ^ (row & 7)) << 3);
  }

  // V^T DMA: wave w covers d-rows w*32+a*8+(lane>>3), 8 chunks of 8 per 128B
  // row; slot lane&7 holds logical chunk (lane&7)^(row&7); row&7 == (lane>>3)&7.
  const int r8 = lane >> 3;
  const int vsc = ((lane & 7) ^ (r8 & 7)) * 8;
  const bf16* Vp = vt + (int64_t)(h * 128 + w * 32 + r8) * 4096 + b * 1024 + vsc;

  auto STAGE = [&](int buf, int kt) {
    const bf16* kn = kbase + (int64_t)kt * 64 * 4096;
#pragma unroll
    for (int c = 0; c < 4; ++c)
      async16(kn + koff[c], &Kb[buf][(w * 16 + c * 4) * 128]);
    const bf16* vn = Vp + kt * 64;
#pragma unroll
    for (int a = 0; a < 4; ++a)
      async16(vn + (int64_t)(a * 8) * 4096, &Vb[buf][(w * 32 + a * 8) * 64]);
  };

  STAGE(0, 0);  // 8 DMA calls in flight
  f32x4 o[8] = {};
  float lrw[4] = {0.f, 0.f, 0.f, 0.f};

  for (int kt = 0; kt < 16; ++kt) {
    const int cur = kt & 1;
    if (kt + 1 < 16) {
      STAGE(cur ^ 1, kt + 1);  // 16 in flight
      // tile kt's 8 oldest done; kt+1's 8 stay in flight across the barrier
      asm volatile("s_waitcnt vmcnt(8)\n\ts_barrier" ::: "memory");
    } else {
      asm volatile("s_waitcnt vmcnt(0)\n\ts_barrier" ::: "memory");
    }

    // S = Q @ K^T  (16 x 64 per wave)
    f32x4 s[4] = {};
    __builtin_amdgcn_s_setprio(1);
#pragma unroll
    for (int nt = 0; nt < 4; ++nt)
#pragma unroll
      for (int ks = 0; ks < 4; ++ks) {
        int key = nt * 16 + l15;
        bf16x8 bfrg = *(const bf16x8*)(
            &Kb[cur][key * 128 + (((ks * 4 + quad) ^ (l15 & 7)) << 3)]);
        s[nt] = MFMA16(qf[ks], bfrg, s[nt]);
      }
    __builtin_amdgcn_s_setprio(0);

    // p = exp(s*scale); lane-local row partials; stash P (block-swizzled)
    float rsum[4] = {0.f, 0.f, 0.f, 0.f};
#pragma unroll
    for (int nt = 0; nt < 4; ++nt)
#pragma unroll
      for (int r = 0; r < 4; ++r) {
        float p = __expf(s[nt][r] * scale);
        rsum[r] += p;
        int row = quad * 4 + r;
        int blk = (nt * 2 + (l15 >> 3)) ^ (quad * 2 + (r >> 1));
        Pl[w][row * 72 + (blk << 3) + (l15 & 7)] = (bf16)p;
      }
#pragma unroll
    for (int r = 0; r < 4; ++r) lrw[r] += rsum[r];

    // O += P @ V  (V^T fragments: conflict-free b128, same pattern as QK)
    __builtin_amdgcn_s_setprio(1);
#pragma unroll
    for (int ks = 0; ks < 2; ++ks) {
      int ablk = (ks * 4 + quad) ^ (l15 >> 1);
      bf16x8 afrg = *(const bf16x8*)(&Pl[w][l15 * 72 + (ablk << 3)]);
#pragma unroll
      for (int dt = 0; dt < 8; ++dt) {
        int d = dt * 16 + l15;
        bf16x8 bfrg = *(const bf16x8*)(
            &Vb[cur][d * 64 + (((ks * 4 + quad) ^ (l15 & 7)) << 3)]);
        o[dt] = MFMA16(afrg, bfrg, o[dt]);
      }
    }
    __builtin_amdgcn_s_setprio(0);
    // all LDS reads retired before next tile's DMA overwrites; DMA stays in flight
    asm volatile("s_waitcnt lgkmcnt(0)\n\ts_barrier" ::: "memory");
  }

  float inv[4];
#pragma unroll
  for (int r = 0; r < 4; ++r) {
    float ssum = lrw[r];
#pragma unroll
    for (int off = 8; off >= 1; off >>= 1) ssum += __shfl_xor(ssum, off, 64);
    inv[r] = 1.0f / ssum;
  }
#pragma unroll
  for (int dt = 0; dt < 8; ++dt)
#pragma unroll
    for (int r = 0; r < 4; ++r) {
      int64_t row = trow + quad * 4 + r;
      int col = h * 128 + dt * 16 + l15;
      attn[row * 2048 + col] = (bf16)(o[dt][r] * inv[r]);
    }
}

// ---------------------------------------------------------------------------
extern "C" void kernel_launch(void* const* d_in, const int* in_sizes, int n_in,
                              void* d_out, int out_size, void* d_ws, size_t ws_size,
                              hipStream_t stream) {
  const float* hidden = (const float*)d_in[0];
  const float* Wdkv = (const float*)d_in[1];
  const float* bdkv = (const float*)d_in[2];
  const float* Wuk  = (const float*)d_in[3];
  const float* buk  = (const float*)d_in[4];
  const float* Wuv  = (const float*)d_in[5];
  const float* buv  = (const float*)d_in[6];
  const float* Wkr  = (const float*)d_in[7];
  const float* bkr  = (const float*)d_in[8];
  const float* Wdq  = (const float*)d_in[9];
  const float* bdq  = (const float*)d_in[10];
  const float* Wuq  = (const float*)d_in[11];
  const float* buq  = (const float*)d_in[12];
  // d_in[13], d_in[14] (W_QR_w/b): dead code in the reference.
  const float* Wo   = (const float*)d_in[15];
  const float* bo   = (const float*)d_in[16];

  // Outputs fp32.
  float* out0 = (float*)d_out;          // [2048][2048]
  float* c_kv = out0 + 4194304;         // [2048][512]
  float* k_r  = out0 + 5242880;         // [32768][64]

  // ---- workspace (25.2 MB) ----
  bf16* DKVQ = (bf16*)d_ws;             // [2048][2048]: cols 0-511 = c_kv bf16,
                                        // cols 512+ = c_q. Later reused for attn out.
  bf16* KV   = DKVQ + 4194304;          // [2048][4096]: cols 0-2047 = K (row-major,
                                        // token-major); V^T at [d][2048+token].

  // ---- transient aliases (lifetimes verified non-overlapping) ----
  bf16* WT   = KV;                      // Wdkv+Wdq bf16 [2048][2048]; dead before KV gemm writes
  bf16* qx   = (bf16*)out0;             // [2048][2048] q (written by UQ gemm)
  bf16* hb   = qx + 4194304;            // hidden bf16; after DKVQ gemm reused for Wuq bf16
  bf16* WUKV = qx;                      // Wuk+Wuv bf16 [4096][512]; dead before UQ gemm writes qx
  bf16* Wuqb = hb;                      // Wuq bf16 [2048][1536]
  bf16* Wob  = (bf16*)k_r;              // Wo bf16 [2048][2048]; k_r written after final gemm

  // 1. all leading converts in one launch: hidden, Wdkv, Wdq, Wuk, Wuv, Wo
  cvt6<<<dim3(2048, 6), 256, 0, stream>>>(
      hidden, hb, 4194304,
      Wdkv, WT, 1048576,
      Wdq, WT + 1048576, 3145728,
      Wuk, WUKV, 1048576,
      Wuv, WUKV + 1048576, 1048576,
      Wo, Wob, 4194304);
  // 2. fused c_kv|c_q gemm: [2048][2048] = hb @ WT^T. fp32 c_kv for n<512.
  gemm_bb<2, false><<<dim3(32, 16), 256, 0, stream>>>(
      hb, 2048, WT, 2048, bdkv, bdq, 512, DKVQ, c_kv, 2048, 2048, 2048, 2048);
  // 3. W_UQ -> bf16 (hb region; hidden bf16 consumed by step 2)
  cvt_f32_bf16<<<1536, 256, 0, stream>>>(Wuq, Wuqb, 3145728);
  // 4. fused K|V gemm (TRANSV): K stored row-major, V stored TRANSPOSED.
  gemm_bb<0, true><<<dim3(64, 16), 256, 0, stream>>>(
      DKVQ, 2048, WUKV, 512, buk, buv, 2048, KV, nullptr, 4096, 2048, 4096, 512);
  // 5. q gemm: qx = cq @ Wuq^T (A = DKVQ cols 512+, lda 2048)
  gemm_bb<0, false><<<dim3(32, 16), 256, 0, stream>>>(
      DKVQ + 512, 2048, Wuqb, 1536, buq, buq, 2048, qx, nullptr, 2048, 2048, 2048, 1536);
  // 6. attention -> DKVQ region (c_kv/c_q bf16 now dead); V^T base = KV + 2048
  attn_fwd<<<dim3(8, 64), 256, 0, stream>>>(qx, KV, KV + 2048, DKVQ);
  // 7. output gemm: out0 = attn @ Wo^T (overwrites qx/hb regions, both dead)
  gemm_bb<1, false><<<dim3(32, 16), 256, 0, stream>>>(
      DKVQ, 2048, Wob, 2048, bo, bo, 2048, nullptr, out0, 2048, 2048, 2048, 2048);
  // 8. k_r rope (reads K region; overwrites Wob which is now dead)
  kr_rope<<<512, 256, 0, stream>>>(KV, Wkr, bkr, k_r);
}